// Round 1
// baseline (1209.437 us; speedup 1.0000x reference)
//
#include <hip/hip_runtime.h>
#include <math.h>

#define NLOC 4096
#define NREP 128
#define MN   48
#define XSS  49   // odd stride -> cheap strided row reads from LDS

// One block per location. 256 threads as a 16x16 grid of 8x8 register tiles:
// thread (ti,tj) owns rows 8*ti..8*ti+7, cols 8*tj..8*tj+7 of the FULL 128x128
// matrix (both triangles kept -> symmetric maintenance lets Cholesky read the
// pivot column as a pivot ROW).
//
// Blocked right-looking Cholesky, 8-wide panels:
//   - panel p (rows 8p..8p+7) is owned by threads tid=16p..16p+15 = 16
//     consecutive lanes of wave p/4 -> factored entirely in-wave via __shfl,
//     no barriers;
//   - normalized panel rows (L^T) published to double-buffered LDS, ONE
//     __syncthreads per panel (16 total vs 128 in the per-column version);
//   - trailing rank-8 update fully in registers, no per-element runtime masks.
// acc[][] is never runtime-indexed (scratch-demotion hazard).
__global__ __launch_bounds__(256, 2)
void otm_fused(const float* __restrict__ aug,
               const float* __restrict__ theta,
               const float* __restrict__ scales,
               const float* __restrict__ nug_mean,
               const int*   __restrict__ batch_idx,
               float* __restrict__ out_g,
               float* __restrict__ out_l)
{
    __shared__ float xs[NREP * XSS];     // 25088 B
    __shared__ float ldiag[NREP];
    __shared__ float scal_s[MN];
    __shared__ float wl[2][8][NREP];     // 8192 B: normalized panel rows (L^T)
    __shared__ float rs_s[NREP];         // 1/sqrt(c_kk) per column

    const int loc = blockIdx.x;
    const int tid = threadIdx.x;
    const int ti  = tid >> 4;
    const int tj  = tid & 15;
    const int i0  = ti << 3;   // first owned row
    const int j0  = tj << 3;   // first owned col

    // --- per-k feature scaling: scal[k] = sqrt(exp(-(k+1)*exp(theta2))) ---
    const float th2 = theta[2];
    if (tid < MN) {
        float e2 = expf(th2);
        scal_s[tid] = expf(-0.5f * (float)(tid + 1) * e2);
    }
    __syncthreads();

    // --- gather aug[:,loc,1:49], NaN->0, scale, into LDS (row-major) ---
    for (int idx = tid; idx < NREP * MN; idx += 256) {
        int r = idx / MN;
        int c = idx - r * MN;
        float v = aug[(r * NLOC + loc) * (MN + 1) + 1 + c];
        v = (v != v) ? 0.0f : v;
        xs[r * XSS + c] = v * scal_s[c];
    }
    __syncthreads();

    // --- row norms (diagonal of Gram), threads 0..127 ---
    if (tid < NREP) {
        float s = 0.0f;
        #pragma unroll
        for (int kk = 0; kk < MN; ++kk) {
            float v = xs[tid * XSS + kk];
            s = fmaf(v, v, s);
        }
        ldiag[tid] = s;
    }

    // --- Gram: acc[r][c] = sum_k xs[i0+r][k]*xs[j0+c][k] ---
    float acc[8][8];
    #pragma unroll
    for (int r = 0; r < 8; ++r)
        #pragma unroll
        for (int c = 0; c < 8; ++c) acc[r][c] = 0.0f;

    for (int kk = 0; kk < MN; ++kk) {
        float a[8], b[8];
        #pragma unroll
        for (int r = 0; r < 8; ++r) a[r] = xs[(i0 + r) * XSS + kk];
        #pragma unroll
        for (int c = 0; c < 8; ++c) b[c] = xs[(j0 + c) * XSS + kk];
        #pragma unroll
        for (int r = 0; r < 8; ++r)
            #pragma unroll
            for (int c = 0; c < 8; ++c)
                acc[r][c] = fmaf(a[r], b[c], acc[r][c]);
    }
    __syncthreads();   // ldiag ready

    // --- elementwise transform: G = (lin + sig2*matern)/nug + I ---
    const float s_loc   = scales[loc];
    const float th3 = theta[3], th4 = theta[4], th5 = theta[5];
    const float sig2    = expf(2.0f * fmaf(logf(s_loc), th4, th3));
    const float nug_inv = 1.0f / nug_mean[loc];
    const float ls      = expf(th5) * 1.7320508075688772f;  // sqrt(2*1.5)
    const float inv_ls2 = 1.0f / (ls * ls);
    const bool  is0     = (batch_idx[loc] == 0);

    float di[8], dj[8];
    #pragma unroll
    for (int r = 0; r < 8; ++r) di[r] = ldiag[i0 + r];
    #pragma unroll
    for (int c = 0; c < 8; ++c) dj[c] = ldiag[j0 + c];

    float* gout = out_g + (size_t)loc * (NREP * NREP);
    #pragma unroll
    for (int r = 0; r < 8; ++r) {
        const int i = i0 + r;
        #pragma unroll
        for (int h = 0; h < 2; ++h) {
            float tmp[4];
            #pragma unroll
            for (int e = 0; e < 4; ++e) {
                const int c = h * 4 + e;
                const int j = j0 + c;
                float lin = acc[r][c];
                float sq  = (di[r] + dj[c] - 2.0f * lin) * inv_ls2;
                sq = fmaxf(sq, 0.0f);
                float d3  = 1.7320508075688772f * sqrtf(sq);
                float mat = (1.0f + d3) * __expf(-d3);
                float gv  = fmaf(sig2, mat, lin) * nug_inv + ((i == j) ? 1.0f : 0.0f);
                if (is0) gv = (i == j) ? 1.0f : 0.0f;
                acc[r][c] = gv;
                tmp[e] = gv;
            }
            *(float4*)(gout + (size_t)i * NREP + j0 + h * 4) =
                make_float4(tmp[0], tmp[1], tmp[2], tmp[3]);
        }
    }

    // --- blocked Cholesky. Invariant: unnormalized c_ij = L_ij * L_jj. ---
    for (int p = 0; p < 16; ++p) {
        // in-wave panel factorization: threads (ti==p, tj>=p), lanes
        // (p%4)*16+tj of wave p/4; diag tile lives on lane (p%4)*16+p.
        if (ti == p && tj >= p) {
            const int diagLane = ((p & 3) << 4) | p;
            float rsv[8];
            #pragma unroll
            for (int s = 0; s < 8; ++s) {
                const float piv  = __shfl(acc[s][s], diagLane);
                const float dinv = 1.0f / piv;
                rsv[s] = 1.0f / sqrtf(piv);
                #pragma unroll
                for (int sp = s + 1; sp < 8; ++sp) {
                    const float f = __shfl(acc[sp][s], diagLane) * dinv;
                    #pragma unroll
                    for (int c = 0; c < 8; ++c) {
                        if (c > s) {                     // compile-time mask (diag tile)
                            acc[sp][c] = fmaf(-f, acc[s][c], acc[sp][c]);
                        } else if (tj > p) {             // cols right of panel: full
                            acc[sp][c] = fmaf(-f, acc[s][c], acc[sp][c]);
                        }
                    }
                }
            }
            // publish normalized panel rows: wl[s][j] = c_{k,j}/sqrt(c_kk) = L_{j,k}
            #pragma unroll
            for (int s = 0; s < 8; ++s) {
                *(float4*)&wl[p & 1][s][j0] =
                    make_float4(acc[s][0] * rsv[s], acc[s][1] * rsv[s],
                                acc[s][2] * rsv[s], acc[s][3] * rsv[s]);
                *(float4*)&wl[p & 1][s][j0 + 4] =
                    make_float4(acc[s][4] * rsv[s], acc[s][5] * rsv[s],
                                acc[s][6] * rsv[s], acc[s][7] * rsv[s]);
            }
            if (tj == p) {
                #pragma unroll
                for (int s = 0; s < 8; ++s) rs_s[(p << 3) + s] = rsv[s];
            }
        }
        __syncthreads();   // the ONLY barrier per panel

        // trailing rank-8 update: rows below the panel only (ti>p).
        if (ti > p) {
            const float (*w)[NREP] = wl[p & 1];
            if (tj > p) {
                // full 8x8x8, no masks
                #pragma unroll 2
                for (int s = 0; s < 8; ++s) {
                    const float4 wiA = *(const float4*)&w[s][i0];
                    const float4 wiB = *(const float4*)&w[s][i0 + 4];
                    const float4 wjA = *(const float4*)&w[s][j0];
                    const float4 wjB = *(const float4*)&w[s][j0 + 4];
                    const float wi[8] = {wiA.x, wiA.y, wiA.z, wiA.w,
                                         wiB.x, wiB.y, wiB.z, wiB.w};
                    const float wj[8] = {wjA.x, wjA.y, wjA.z, wjA.w,
                                         wjB.x, wjB.y, wjB.z, wjB.w};
                    #pragma unroll
                    for (int r = 0; r < 8; ++r)
                        #pragma unroll
                        for (int c = 0; c < 8; ++c)
                            acc[r][c] = fmaf(-wi[r], wj[c], acc[r][c]);
                }
            } else if (tj == p) {
                // panel columns below the diag block: only k < j terms (s < c),
                // all masks compile-time.
                #pragma unroll
                for (int s = 0; s < 7; ++s) {
                    const float4 wiA = *(const float4*)&w[s][i0];
                    const float4 wiB = *(const float4*)&w[s][i0 + 4];
                    const float wi[8] = {wiA.x, wiA.y, wiA.z, wiA.w,
                                         wiB.x, wiB.y, wiB.z, wiB.w};
                    #pragma unroll
                    for (int c = 0; c < 8; ++c) {
                        if (c > s) {
                            const float wjc = w[s][j0 + c];
                            #pragma unroll
                            for (int r = 0; r < 8; ++r)
                                acc[r][c] = fmaf(-wi[r], wjc, acc[r][c]);
                        }
                    }
                }
            }
        }
    }

    // --- epilogue: L[i][j] = c_ij / sqrt(c_jj), zeros above diagonal ---
    float rsj[8];
    #pragma unroll
    for (int c = 0; c < 8; ++c) rsj[c] = rs_s[j0 + c];

    float* lout = out_l + (size_t)loc * (NREP * NREP);
    #pragma unroll
    for (int r = 0; r < 8; ++r) {
        const int i = i0 + r;
        #pragma unroll
        for (int h = 0; h < 2; ++h) {
            float tmp[4];
            #pragma unroll
            for (int e = 0; e < 4; ++e) {
                const int c = h * 4 + e;
                const int j = j0 + c;
                tmp[e] = (i >= j) ? acc[r][c] * rsj[c] : 0.0f;
            }
            *(float4*)(lout + (size_t)i * NREP + j0 + h * 4) =
                make_float4(tmp[0], tmp[1], tmp[2], tmp[3]);
        }
    }
}

extern "C" void kernel_launch(void* const* d_in, const int* in_sizes, int n_in,
                              void* d_out, int out_size, void* d_ws, size_t ws_size,
                              hipStream_t stream) {
    const float* aug    = (const float*)d_in[0];
    const float* theta  = (const float*)d_in[1];
    const float* scales = (const float*)d_in[2];
    const float* nug    = (const float*)d_in[3];
    const int*   bidx   = (const int*)d_in[4];
    float* g = (float*)d_out;
    float* l = g + (size_t)NLOC * NREP * NREP;
    hipLaunchKernelGGL(otm_fused, dim3(NLOC), dim3(256), 0, stream,
                       aug, theta, scales, nug, bidx, g, l);
}